// Round 4
// baseline (531.031 us; speedup 1.0000x reference)
//
#include <hip/hip_runtime.h>
#include <cstdint>
#include <cstddef>

typedef float   f32x4 __attribute__((ext_vector_type(4)));
typedef _Float16 f16x8 __attribute__((ext_vector_type(8)));
typedef _Float16 f16x4 __attribute__((ext_vector_type(4)));

#define TOK  4096
#define HID  1024
#define IDIM 4096
#define PSTR 1056   // padded token-row stride (1024 data + 1 one + 31 zeros)
#define MSTR 576    // mixed-GEMM K stride (512 wdown + 8 probs + 56 zeros)

#define GAS __attribute__((address_space(1)))
#define LAS __attribute__((address_space(3)))

__device__ __forceinline__ void gld16(const void* g, void* l) {
    __builtin_amdgcn_global_load_lds((const GAS unsigned int*)g,
                                     (LAS unsigned int*)l, 16, 0, 0);
}

// ---------------------------------------------------------------------------
// Dense: part[z] = hs(fp32)@dense_w^T over K-chunk. 128x128 tile, BK=32,
// sk=2 -> grid (32,8,2)=512 blocks (2/CU). A: direct global->reg fp32->f16.
// B: async LDS, bank-swizzled slots (kc+(row>>1))&3 -> conflict-free reads.
// 4 waves 2x2, wave 64x64 (4x4 MFMA).
// ---------------------------------------------------------------------------
__global__ __launch_bounds__(256) void gemm_dense(
    const float* __restrict__ Af, const _Float16* __restrict__ B,
    float* __restrict__ part)
{
    __shared__ _Float16 lB[128 * 32];
    const int tid = threadIdx.x, lane = tid & 63, wave = tid >> 6;
    const int m0 = blockIdx.x * 128;
    const int n0 = blockIdx.y * 128;
    const int kz0 = blockIdx.z * 2048;
    const int wM = (wave & 1) * 64;
    const int wN = (wave >> 1) * 64;
    const _Float16* gB[2];
    _Float16* lw[2];
#pragma unroll
    for (int j = 0; j < 2; ++j) {
        const int q = tid + j * 256;
        const int row = q >> 2;
        const int kc = ((q & 3) - (row >> 1)) & 3;
        gB[j] = B + (size_t)(n0 + row) * IDIM + kz0 + kc * 8;
        lw[j] = lB + q * 8;
    }
    const int fr = lane & 15, kcq = lane >> 4, kc8 = kcq * 8;
    const float* aptr[4];
#pragma unroll
    for (int mi = 0; mi < 4; ++mi)
        aptr[mi] = Af + (size_t)(m0 + wM + mi * 16 + fr) * IDIM + kz0 + kc8;
    int boff[4];
#pragma unroll
    for (int ni = 0; ni < 4; ++ni) {
        const int r = wN + ni * 16 + fr;
        boff[ni] = r * 32 + ((kcq + (fr >> 1)) & 3) * 8;
    }
    f32x4 acc[4][4] = {};
    for (int k0 = 0; k0 < 2048; k0 += 32) {
        gld16(gB[0] + k0, lw[0]);
        gld16(gB[1] + k0, lw[1]);
        f16x8 a[4];
#pragma unroll
        for (int mi = 0; mi < 4; ++mi) {
            f32x4 lo = *(const f32x4*)(aptr[mi] + k0);
            f32x4 hi = *(const f32x4*)(aptr[mi] + k0 + 4);
#pragma unroll
            for (int j = 0; j < 4; ++j) {
                a[mi][j] = (_Float16)lo[j];
                a[mi][4 + j] = (_Float16)hi[j];
            }
        }
        __syncthreads();
        f16x8 b[4];
#pragma unroll
        for (int ni = 0; ni < 4; ++ni) b[ni] = *(const f16x8*)(lB + boff[ni]);
#pragma unroll
        for (int mi = 0; mi < 4; ++mi)
#pragma unroll
            for (int ni = 0; ni < 4; ++ni)
                acc[mi][ni] = __builtin_amdgcn_mfma_f32_16x16x32_f16(
                    a[mi], b[ni], acc[mi][ni], 0, 0, 0);
        __syncthreads();
    }
    float* dst = part + (size_t)blockIdx.z * TOK * HID;
    const int cn = lane & 15, rq = (lane >> 4) * 4;
#pragma unroll
    for (int mi = 0; mi < 4; ++mi)
#pragma unroll
        for (int r = 0; r < 4; ++r) {
            const int m = m0 + wM + mi * 16 + rq + r;
#pragma unroll
            for (int ni = 0; ni < 4; ++ni) {
                const int n = n0 + wN + ni * 16 + cn;
                dst[(size_t)m * HID + n] = acc[mi][ni][r];
            }
        }
}

// ---------------------------------------------------------------------------
// f16 GEMM: C[Mx?] = A[MxK] @ B[?xK]^T. Tile 64x128, BK=32, 256 thr, 4 waves
// 1x4 (wave 64x32, 4x2 MFMA). A: direct global frags. B: async swizzled LDS.
// Biases are folded into K columns by the caller. Modes:
//  0 dual(z): z0 out=relu(v)->down ; z1 out=v->g            (f16, ldC)
//  1 mixed : f16 = v + addvH[idx]                            (ldC)
//  2 fuse  : f32 = v + addvF[idx]                            (ldC)
//  3 plain : f16 = v                                         (ldC)
// ---------------------------------------------------------------------------
template <int MODE>
__global__ __launch_bounds__(256) void gemmF(
    const _Float16* __restrict__ A, const _Float16* __restrict__ B,
    int K, int ldC,
    _Float16* __restrict__ outH, float* __restrict__ outF,
    const _Float16* __restrict__ addvH, const float* __restrict__ addvF,
    const _Float16* __restrict__ A2, const _Float16* __restrict__ B2,
    _Float16* __restrict__ outH2)
{
    __shared__ _Float16 lB[128 * 32];
    const int tid = threadIdx.x, lane = tid & 63, wave = tid >> 6;
    int zz = 0;
    if constexpr (MODE == 0) {
        zz = blockIdx.z;
        if (zz) { A = A2; B = B2; outH = outH2; }
    }
    const int m0 = blockIdx.x * 64;
    const int n0 = blockIdx.y * 128;
    const int wN = wave * 32;
    const _Float16* gB[2];
    _Float16* lw[2];
#pragma unroll
    for (int j = 0; j < 2; ++j) {
        const int q = tid + j * 256;
        const int row = q >> 2;
        const int kc = ((q & 3) - (row >> 1)) & 3;
        gB[j] = B + (size_t)(n0 + row) * K + kc * 8;
        lw[j] = lB + q * 8;
    }
    const int fr = lane & 15, kcq = lane >> 4, kc8 = kcq * 8;
    const _Float16* aptr[4];
#pragma unroll
    for (int mi = 0; mi < 4; ++mi)
        aptr[mi] = A + (size_t)(m0 + mi * 16 + fr) * K + kc8;
    int boff[2];
#pragma unroll
    for (int ni = 0; ni < 2; ++ni) {
        const int r = wN + ni * 16 + fr;
        boff[ni] = r * 32 + ((kcq + (fr >> 1)) & 3) * 8;
    }
    f32x4 acc[4][2] = {};
    for (int k0 = 0; k0 < K; k0 += 32) {
        gld16(gB[0] + k0, lw[0]);
        gld16(gB[1] + k0, lw[1]);
        f16x8 a[4];
#pragma unroll
        for (int mi = 0; mi < 4; ++mi)
            a[mi] = *(const f16x8*)(aptr[mi] + k0);
        __syncthreads();
        f16x8 b[2];
#pragma unroll
        for (int ni = 0; ni < 2; ++ni) b[ni] = *(const f16x8*)(lB + boff[ni]);
#pragma unroll
        for (int mi = 0; mi < 4; ++mi)
#pragma unroll
            for (int ni = 0; ni < 2; ++ni)
                acc[mi][ni] = __builtin_amdgcn_mfma_f32_16x16x32_f16(
                    a[mi], b[ni], acc[mi][ni], 0, 0, 0);
        __syncthreads();
    }
    const int cn = lane & 15, rq = (lane >> 4) * 4;
#pragma unroll
    for (int mi = 0; mi < 4; ++mi)
#pragma unroll
        for (int r = 0; r < 4; ++r) {
            const int m = m0 + mi * 16 + rq + r;
#pragma unroll
            for (int ni = 0; ni < 2; ++ni) {
                const int n = n0 + wN + ni * 16 + cn;
                const size_t idx = (size_t)m * ldC + n;
                const float v = acc[mi][ni][r];
                if constexpr (MODE == 0) {
                    outH[idx] = (_Float16)(zz ? v : (v > 0.f ? v : 0.f));
                } else if constexpr (MODE == 1) {
                    outH[idx] = (_Float16)(v + (float)addvH[idx]);
                } else if constexpr (MODE == 2) {
                    outF[idx] = v + addvF[idx];
                } else {
                    outH[idx] = (_Float16)v;
                }
            }
        }
}

// ---------------------------------------------------------------------------
// split-K reduce + bias + LN. h=p0+p1+dense_b; pn=h+it; ai=LN(pn).
// ai/pn get stride PSTR with col1024=1, cols 1025..1055=0 (bias folding).
// ---------------------------------------------------------------------------
__global__ __launch_bounds__(256) void ln_fused(
    const float* __restrict__ part, const float* __restrict__ dbias,
    const float* __restrict__ it, const float* __restrict__ gam,
    const float* __restrict__ bet, _Float16* __restrict__ h16,
    _Float16* __restrict__ ai, _Float16* __restrict__ pn)
{
    const int n = blockIdx.x, tid = threadIdx.x;
    const int lane = tid & 63, wave = tid >> 6;
    const size_t base = (size_t)n * 1024 + tid * 4;
    f32x4 h = *(const f32x4*)(dbias + tid * 4);
    h += *(const f32x4*)(part + base);
    h += *(const f32x4*)(part + (size_t)TOK * HID + base);
    f16x4 hv;
#pragma unroll
    for (int j = 0; j < 4; ++j) hv[j] = (_Float16)h[j];
    *(f16x4*)(h16 + base) = hv;
    f32x4 x = h + *(const f32x4*)(it + base);
    float s = x[0] + x[1] + x[2] + x[3];
    float q = x[0] * x[0] + x[1] * x[1] + x[2] * x[2] + x[3] * x[3];
#pragma unroll
    for (int off = 1; off < 64; off <<= 1) {
        s += __shfl_xor(s, off);
        q += __shfl_xor(q, off);
    }
    __shared__ float rs[4], rq[4];
    if (lane == 0) { rs[wave] = s; rq[wave] = q; }
    __syncthreads();
    s = rs[0] + rs[1] + rs[2] + rs[3];
    q = rq[0] + rq[1] + rq[2] + rq[3];
    const float mu = s * (1.f / 1024.f);
    const float var = q * (1.f / 1024.f) - mu * mu;
    const float rstd = rsqrtf(var + 1e-12f);
    f32x4 gv = *(const f32x4*)(gam + tid * 4);
    f32x4 bv = *(const f32x4*)(bet + tid * 4);
    f16x4 av, pv;
#pragma unroll
    for (int j = 0; j < 4; ++j) {
        const float y = (x[j] - mu) * rstd * gv[j] + bv[j];
        av[j] = (_Float16)y;
        pv[j] = (_Float16)x[j];
    }
    const size_t pb = (size_t)n * PSTR + tid * 4;
    *(f16x4*)(ai + pb) = av;
    *(f16x4*)(pn + pb) = pv;
    if (tid < 8) {
        f16x4 z;
#pragma unroll
        for (int j = 0; j < 4; ++j) z[j] = (_Float16)0.f;
        if (tid == 0) z[0] = (_Float16)1.f;
        const size_t qb = (size_t)n * PSTR + 1024 + tid * 4;
        *(f16x4*)(ai + qb) = z;
        *(f16x4*)(pn + qb) = z;
    }
}

__global__ __launch_bounds__(256) void ln_out(
    const float* __restrict__ fuse, const float* __restrict__ gam,
    const float* __restrict__ bet, float* __restrict__ outp)
{
    const int n = blockIdx.x, tid = threadIdx.x;
    const int lane = tid & 63, wave = tid >> 6;
    const size_t base = (size_t)n * 1024 + tid * 4;
    f32x4 x = *(const f32x4*)(fuse + base);
    float s = x[0] + x[1] + x[2] + x[3];
    float q = x[0] * x[0] + x[1] * x[1] + x[2] * x[2] + x[3] * x[3];
#pragma unroll
    for (int off = 1; off < 64; off <<= 1) {
        s += __shfl_xor(s, off);
        q += __shfl_xor(q, off);
    }
    __shared__ float rs[4], rq[4];
    if (lane == 0) { rs[wave] = s; rq[wave] = q; }
    __syncthreads();
    s = rs[0] + rs[1] + rs[2] + rs[3];
    q = rq[0] + rq[1] + rq[2] + rq[3];
    const float mu = s * (1.f / 1024.f);
    const float var = q * (1.f / 1024.f) - mu * mu;
    const float rstd = rsqrtf(var + 1e-12f);
    f32x4 gv = *(const f32x4*)(gam + tid * 4);
    f32x4 bv = *(const f32x4*)(bet + tid * 4);
    f32x4 y;
#pragma unroll
    for (int j = 0; j < 4; ++j) y[j] = (x[j] - mu) * rstd * gv[j] + bv[j];
    *(f32x4*)(outp + base) = y;
}

// ---------------------------------------------------------------------------
// scores + softmax over T; wdownP = [probs*down | probs_f16 | zeros] (MSTR).
// ---------------------------------------------------------------------------
__global__ __launch_bounds__(256) void scores2(
    const _Float16* __restrict__ pn, const float* __restrict__ U9,
    const float* __restrict__ cts,
    const _Float16* __restrict__ down, const _Float16* __restrict__ g,
    _Float16* __restrict__ wdownP)
{
    const int n = blockIdx.x, tid = threadIdx.x;
    const int lane = tid & 63, wave = tid >> 6;
    const _Float16* prow = pn + (size_t)n * PSTR;
    float a9[9] = {};
#pragma unroll
    for (int j = 0; j < 4; ++j) {
        const int h = tid + j * 256;
        const float ph = (float)prow[h];
        const float* u = U9 + h * 12;
        f32x4 u0 = *(const f32x4*)u;
        f32x4 u1 = *(const f32x4*)(u + 4);
#pragma unroll
        for (int k = 0; k < 4; ++k) { a9[k] += ph * u0[k]; a9[4 + k] += ph * u1[k]; }
        a9[8] += ph * u[8];
    }
#pragma unroll
    for (int off = 1; off < 64; off <<= 1)
#pragma unroll
        for (int k = 0; k < 9; ++k) a9[k] += __shfl_xor(a9[k], off);
    __shared__ float red[4][9];
    __shared__ float sd[8];
    __shared__ float pl[8];
    if (lane == 0)
#pragma unroll
        for (int k = 0; k < 9; ++k) red[wave][k] = a9[k];
    const int c0i = tid * 2;
    const size_t dbase = (size_t)n * 512;
    const float d0 = (float)down[dbase + c0i];
    const float d1 = (float)down[dbase + c0i + 1];
    float pz = d0 * (float)g[dbase + c0i] + d1 * (float)g[dbase + c0i + 1];
#pragma unroll
    for (int off = 1; off < 32; off <<= 1) pz += __shfl_xor(pz, off);
    if ((lane & 31) == 0) sd[wave * 2 + (lane >> 5)] = pz;
    __syncthreads();
    if (tid == 0) {
        float qb = cts[8];
#pragma unroll
        for (int w = 0; w < 4; ++w) qb += red[w][8];
        float sc[8];
        float mx = -1e30f;
#pragma unroll
        for (int t = 0; t < 8; ++t) {
            float v = sd[t] + cts[t] + qb;
#pragma unroll
            for (int w = 0; w < 4; ++w) v += red[w][t];
            sc[t] = v;
            mx = fmaxf(mx, v);
        }
        float sum = 0.f;
#pragma unroll
        for (int t = 0; t < 8; ++t) { sc[t] = expf(sc[t] - mx); sum += sc[t]; }
        const float inv = 1.f / sum;
#pragma unroll
        for (int t = 0; t < 8; ++t) pl[t] = sc[t] * inv;
    }
    __syncthreads();
    _Float16* wd = wdownP + (size_t)n * MSTR;
    const float pr = pl[c0i >> 6];
    wd[c0i]     = (_Float16)(pr * d0);
    wd[c0i + 1] = (_Float16)(pr * d1);
    if (tid < 64)
        wd[512 + tid] = (tid < 8) ? (_Float16)pl[tid] : (_Float16)0.f;
}

// ---------------------------------------------------------------------------
// prep: all weight conversions, reshapes, bias-column folding
// ---------------------------------------------------------------------------
__device__ inline void cvt_seg(const float* __restrict__ s, _Float16* __restrict__ d,
                               int n4, int gid, int gsz)
{
    for (int i = gid; i < n4; i += gsz) {
        f32x4 v = ((const f32x4*)s)[i];
        f16x4 o;
        o[0] = (_Float16)v[0]; o[1] = (_Float16)v[1];
        o[2] = (_Float16)v[2]; o[3] = (_Float16)v[3];
        ((f16x4*)d)[i] = o;
    }
}

__global__ __launch_bounds__(256) void prep_all(
    const float* dw, _Float16* o_dw,
    const float* vw, _Float16* o_vw,
    const float* kw, _Float16* o_kw,
    const float* upw, const float* upb, _Float16* o_upg, _Float16* o_upmix,
    const float* dnw, const float* dnb, _Float16* o_dn)
{
    const int gid = blockIdx.x * 256 + threadIdx.x;
    const int gsz = gridDim.x * 256;
    cvt_seg(dw, o_dw, HID * IDIM / 4, gid, gsz);
    cvt_seg(vw, o_vw, HID * HID / 4, gid, gsz);
    cvt_seg(kw, o_kw, HID * HID / 4, gid, gsz);
    for (int i = gid; i < 8 * HID * 64; i += gsz) {
        const int d = i & 63;
        const int h = (i >> 6) & 1023;
        const int t = i >> 16;
        const _Float16 v = (_Float16)upw[i];
        o_upg[(size_t)(t * 64 + d) * 1024 + h] = v;
        o_upmix[(size_t)h * MSTR + t * 64 + d] = v;
    }
    for (int j = gid; j < 1024 * 64; j += gsz) {
        const int h = j >> 6, c = j & 63;
        o_upmix[(size_t)h * MSTR + 512 + c] =
            (c < 8) ? (_Float16)upb[c * 1024 + h] : (_Float16)0.f;
    }
    for (int i = gid; i < 512 * 1024; i += gsz) {
        const int td = i >> 10, h = i & 1023;
        o_dn[(size_t)td * PSTR + h] = (_Float16)dnw[i];
    }
    for (int j = gid; j < 512 * 32; j += gsz) {
        const int td = j >> 5, c = j & 31;
        o_dn[(size_t)td * PSTR + 1024 + c] =
            (c == 0) ? (_Float16)dnb[td] : (_Float16)0.f;
    }
}

__global__ __launch_bounds__(256) void transpose_q(
    const float* __restrict__ in, _Float16* __restrict__ outp)
{
    __shared__ float t[32][33];
    const int bx = blockIdx.x * 32;
    const int by = blockIdx.y * 32;
    const int tx = threadIdx.x & 31, ty = threadIdx.x >> 5;
#pragma unroll
    for (int j = 0; j < 32; j += 8)
        t[ty + j][tx] = in[(size_t)(by + ty + j) * 1024 + bx + tx];
    __syncthreads();
#pragma unroll
    for (int j = 0; j < 32; j += 8)
        outp[(size_t)(bx + ty + j) * 1024 + by + tx] = (_Float16)t[tx][ty + j];
}

// sv1: V[q,t] = key_w[q,:]·up_b[t,:] ; cts[8] = query_b·key_b
__global__ __launch_bounds__(256) void sv1(
    const float* __restrict__ key_w, const float* __restrict__ up_b,
    const float* __restrict__ query_b, const float* __restrict__ key_b,
    float* __restrict__ V, float* __restrict__ cts)
{
    const int b = blockIdx.x, tid = threadIdx.x;
    if (b < 32) {
        const int q = b * 32 + (tid >> 3);
        const int t = tid & 7;
        const f32x4* kr = (const f32x4*)(key_w + (size_t)q * 1024);
        const f32x4* ur = (const f32x4*)(up_b + (size_t)t * 1024);
        float acc = 0.f;
        for (int i = 0; i < 256; ++i) {
            f32x4 a = kr[i], u = ur[i];
            acc += a[0] * u[0] + a[1] * u[1] + a[2] * u[2] + a[3] * u[3];
        }
        V[q * 8 + t] = acc;
    } else {
        float acc = 0.f;
        for (int q = tid; q < 1024; q += 256) acc += query_b[q] * key_b[q];
#pragma unroll
        for (int off = 1; off < 64; off <<= 1) acc += __shfl_xor(acc, off);
        __shared__ float r[4];
        if ((tid & 63) == 0) r[tid >> 6] = acc;
        __syncthreads();
        if (tid == 0) cts[8] = r[0] + r[1] + r[2] + r[3];
    }
}

// sv2: U9 cols 0-7 (w_qT·V) + col 8 (key_b@query_w via w_qT);
//      WgTB bias col (P·query_b) + zero pads; cts 0-7 (query_b·V)
__global__ __launch_bounds__(256) void sv2(
    const _Float16* __restrict__ w_qT, const _Float16* __restrict__ P,
    const float* __restrict__ V, const float* __restrict__ query_b,
    const float* __restrict__ key_b,
    float* __restrict__ U9, _Float16* __restrict__ WgTB, float* __restrict__ cts)
{
    const int b = blockIdx.x, tid = threadIdx.x;
    if (b < 32) {
        const int h = b * 32 + (tid >> 3);
        const int t = tid & 7;
        const _Float16* wr = w_qT + (size_t)h * 1024;
        float acc = 0.f;
        for (int q0 = 0; q0 < 1024; q0 += 4) {
            f16x4 w = *(const f16x4*)(wr + q0);
            acc += (float)w[0] * V[q0 * 8 + t] + (float)w[1] * V[(q0 + 1) * 8 + t]
                 + (float)w[2] * V[(q0 + 2) * 8 + t] + (float)w[3] * V[(q0 + 3) * 8 + t];
        }
        U9[h * 12 + t] = acc;
    } else if (b < 36) {
        const int h1 = (b - 32) * 256 + tid;
        const _Float16* wr = w_qT + (size_t)h1 * 1024;
        float acc = 0.f;
        for (int q0 = 0; q0 < 1024; q0 += 8) {
            f16x8 w = *(const f16x8*)(wr + q0);
            f32x4 k0 = *(const f32x4*)(key_b + q0);
            f32x4 k1 = *(const f32x4*)(key_b + q0 + 4);
#pragma unroll
            for (int j = 0; j < 4; ++j)
                acc += (float)w[j] * k0[j] + (float)w[4 + j] * k1[j];
        }
        U9[h1 * 12 + 8] = acc;
    } else if (b < 38) {
        const int td = (b - 36) * 256 + tid;
        const _Float16* pr = P + (size_t)td * 1024;
        float acc = 0.f;
        for (int q0 = 0; q0 < 1024; q0 += 8) {
            f16x8 w = *(const f16x8*)(pr + q0);
            f32x4 k0 = *(const f32x4*)(query_b + q0);
            f32x4 k1 = *(const f32x4*)(query_b + q0 + 4);
#pragma unroll
            for (int j = 0; j < 4; ++j)
                acc += (float)w[j] * k0[j] + (float)w[4 + j] * k1[j];
        }
        WgTB[(size_t)td * PSTR + 1024] = (_Float16)acc;
        for (int c = 1; c < 32; ++c)
            WgTB[(size_t)td * PSTR + 1024 + c] = (_Float16)0.f;
    } else {
        const int t = tid >> 5;
        float acc = 0.f;
        for (int q = tid & 31; q < 1024; q += 32) acc += V[q * 8 + t] * query_b[q];
#pragma unroll
        for (int off = 1; off < 32; off <<= 1) acc += __shfl_xor(acc, off);
        if ((tid & 31) == 0) cts[t] = acc;
    }
}

// ---------------------------------------------------------------------------
extern "C" void kernel_launch(void* const* d_in, const int* in_sizes, int n_in,
                              void* d_out, int out_size, void* d_ws, size_t ws_size,
                              hipStream_t stream)
{
    const float* hs      = (const float*)d_in[0];
    const float* it      = (const float*)d_in[1];
    const float* dense_w = (const float*)d_in[2];
    const float* dense_b = (const float*)d_in[3];
    const float* ln_g    = (const float*)d_in[4];
    const float* ln_b    = (const float*)d_in[5];
    const float* down_w  = (const float*)d_in[6];
    const float* down_b  = (const float*)d_in[7];
    const float* up_w    = (const float*)d_in[8];
    const float* up_b    = (const float*)d_in[9];
    const float* key_w   = (const float*)d_in[10];
    const float* key_b   = (const float*)d_in[11];
    const float* query_w = (const float*)d_in[12];
    const float* query_b = (const float*)d_in[13];
    const float* value_w = (const float*)d_in[14];
    float* outp = (float*)d_out;
    (void)in_sizes; (void)n_in; (void)out_size; (void)ws_size;

    const size_t MiB = 1048576ull;
    char* base = (char*)d_ws;
    _Float16* w_dense = (_Float16*)(base);                    // 8 MiB
    _Float16* w_value = (_Float16*)(base + 8 * MiB);          // 2
    _Float16* w_key16 = (_Float16*)(base + 10 * MiB);         // 2
    _Float16* w_qT    = (_Float16*)(base + 12 * MiB);         // 2
    _Float16* w_upg   = (_Float16*)(base + 14 * MiB);         // 1
    _Float16* upmixP  = (_Float16*)(base + 15 * MiB);         // 1.125 [1024xMSTR]
    _Float16* w_downB = (_Float16*)(base + 16 * MiB + 262144);// 1.03  [512xPSTR]
    _Float16* WgTB    = (_Float16*)(base + 17 * MiB + 524288);// 1.03  [512xPSTR]
    _Float16* P       = (_Float16*)(base + 18 * MiB + 786432);// 1     [512x1024]
    float*    U9      = (float*)(base + 19 * MiB + 786432);   // 48 KiB [1024][12]
    float*    V       = (float*)(base + 19 * MiB + 835584);   // 32 KiB
    float*    cts     = (float*)(base + 19 * MiB + 868352);   // 64 B
    _Float16* h16     = (_Float16*)(base + 20 * MiB);         // 8 MiB
    _Float16* ai      = (_Float16*)(base + 28 * MiB);         // 8.25 [4096xPSTR]
    _Float16* pn      = (_Float16*)(base + 36 * MiB + 262144);// 8.25
    char* X = base + 45 * MiB;                                // 32 MiB region
    float*    part   = (float*)X;                             // 2x16 MiB (dense)
    _Float16* down   = (_Float16*)X;                          // 4 MiB (post-LN)
    _Float16* g      = (_Float16*)(X + 4 * MiB);              // 4 MiB
    _Float16* wdownP = (_Float16*)(X + 8 * MiB);              // 4.5 [4096xMSTR]
    float*    fuse   = (float*)(X + 13 * MiB);                // 16 MiB
    _Float16* mixed  = ai;                                    // reuse (dead)

    // 1. weight prep (cvt + reshapes + bias-column folding)
    prep_all<<<1024, 256, 0, stream>>>(dense_w, w_dense, value_w, w_value,
                                       key_w, w_key16, up_w, up_b, w_upg, upmixP,
                                       down_w, down_b, w_downB);
    // 2. w_qT = query_w^T (f16)
    transpose_q<<<dim3(32, 32), 256, 0, stream>>>(query_w, w_qT);
    // 3. V[q,t], cts[8]
    sv1<<<33, 256, 0, stream>>>(key_w, up_b, query_b, key_b, V, cts);
    // 4. dense partials (sk=2)
    gemm_dense<<<dim3(32, 8, 2), 256, 0, stream>>>(hs, w_dense, part);
    // 5. reduce + LN -> h16, ai, pn (padded)
    ln_fused<<<TOK, 256, 0, stream>>>(part, dense_b, it, ln_g, ln_b, h16, ai, pn);
    // 6. P = w_upg @ w_key16^T   [512x1024]
    gemmF<3><<<dim3(8, 8), 256, 0, stream>>>(
        w_upg, w_key16, HID, HID, P, nullptr, nullptr, nullptr,
        nullptr, nullptr, nullptr);
    // 7. WgTB(cols 0..1023) = P @ w_qT^T   [512x1024], ldC=PSTR
    gemmF<3><<<dim3(8, 8), 256, 0, stream>>>(
        P, w_qT, HID, PSTR, WgTB, nullptr, nullptr, nullptr,
        nullptr, nullptr, nullptr);
    // 8. U9, WgTB bias col, cts 0-7
    sv2<<<39, 256, 0, stream>>>(w_qT, P, V, query_b, key_b, U9, WgTB, cts);
    // 9. dual: down = relu(ai @ w_downB^T); g = pn @ WgTB^T   (K=PSTR)
    gemmF<0><<<dim3(64, 4, 2), 256, 0, stream>>>(
        ai, w_downB, PSTR, 512, down, nullptr, nullptr, nullptr,
        pn, WgTB, g);
    // 10. scores -> softmax -> wdownP (incl probs cols + zero pad)
    scores2<<<TOK, 256, 0, stream>>>(pn, U9, cts, down, g, wdownP);
    // 11. mixed = wdownP @ upmixP^T + h16   (K=MSTR covers probs@up_b)
    gemmF<1><<<dim3(64, 8), 256, 0, stream>>>(
        wdownP, upmixP, MSTR, HID, mixed, nullptr, h16, nullptr,
        nullptr, nullptr, nullptr);
    // 12. fuse = mixed @ w_value^T + it (f32)
    gemmF<2><<<dim3(64, 8), 256, 0, stream>>>(
        mixed, w_value, HID, HID, nullptr, fuse, nullptr, it,
        nullptr, nullptr, nullptr);
    // 13. out = LN(fuse)
    ln_out<<<TOK, 256, 0, stream>>>(fuse, ln_g, ln_b, outp);
}

// Round 5
// 429.117 us; speedup vs baseline: 1.2375x; 1.2375x over previous
//
#include <hip/hip_runtime.h>
#include <cstdint>
#include <cstddef>

typedef float   f32x4 __attribute__((ext_vector_type(4)));
typedef _Float16 f16x8 __attribute__((ext_vector_type(8)));
typedef _Float16 f16x4 __attribute__((ext_vector_type(4)));

#define TOK  4096
#define HID  1024
#define IDIM 4096
#define PSTR 1056   // padded token-row stride (1024 data + 1 one + 31 zeros)
#define MSTR 576    // mixed-GEMM K stride (512 wdown + 8 probs + 56 zeros)

#define GAS __attribute__((address_space(1)))
#define LAS __attribute__((address_space(3)))

__device__ __forceinline__ void gld16(const void* g, void* l) {
    __builtin_amdgcn_global_load_lds((const GAS unsigned int*)g,
                                     (LAS unsigned int*)l, 16, 0, 0);
}

// ---------------------------------------------------------------------------
// Dense: part[z] = hs(fp32)@dense_w^T over K-chunk of 2048. 128x128 tile,
// BK=32, sk=2 -> grid (32,8,2)=512 (2 blocks/CU). BOTH operands staged via
// global_load_lds: A fp32 (16 KB, XOR slot swizzle), B f16 (8 KB, R4 swizzle).
// cvt fp32->f16 after ds_read. 4 waves 2x2, wave 64x64 (4x4 MFMA 16x16x32).
// ---------------------------------------------------------------------------
__global__ __launch_bounds__(256) void gemm_dense(
    const float* __restrict__ Af, const _Float16* __restrict__ B,
    float* __restrict__ part)
{
    __shared__ float    lA[128 * 32];   // 16 KB
    __shared__ _Float16 lB[128 * 32];   //  8 KB
    const int tid = threadIdx.x, lane = tid & 63, wave = tid >> 6;
    const int m0 = blockIdx.x * 128;
    const int n0 = blockIdx.y * 128;
    const int kz0 = blockIdx.z * 2048;
    const int wM = (wave & 1) * 64;
    const int wN = (wave >> 1) * 64;

    // A staging: 1024 chunks of 16B (4 floats); slot q holds source kc = (q&7)^(row&7)
    const float* gA[4]; float* lwA[4];
#pragma unroll
    for (int j = 0; j < 4; ++j) {
        const int q = j * 256 + tid;
        const int row = q >> 3;
        const int kc = (q & 7) ^ (row & 7);
        gA[j] = Af + (size_t)(m0 + row) * IDIM + kz0 + kc * 4;
        lwA[j] = lA + q * 4;
    }
    // B staging: 512 chunks of 16B (8 halfs); slot q holds kc = ((q&3)-(row>>1))&3
    const _Float16* gB[2]; _Float16* lwB[2];
#pragma unroll
    for (int j = 0; j < 2; ++j) {
        const int q = j * 256 + tid;
        const int row = q >> 2;
        const int kc = ((q & 3) - (row >> 1)) & 3;
        gB[j] = B + (size_t)(n0 + row) * IDIM + kz0 + kc * 8;
        lwB[j] = lB + q * 8;
    }
    const int fr = lane & 15, kcq = lane >> 4;
    int aoff[4][2], boff[4];
#pragma unroll
    for (int mi = 0; mi < 4; ++mi) {
        const int r = wM + mi * 16 + fr;
#pragma unroll
        for (int t = 0; t < 2; ++t)
            aoff[mi][t] = r * 32 + (((2 * kcq + t) ^ (r & 7)) * 4);
    }
#pragma unroll
    for (int ni = 0; ni < 4; ++ni) {
        const int r = wN + ni * 16 + fr;
        boff[ni] = r * 32 + ((kcq + (fr >> 1)) & 3) * 8;
    }

    f32x4 acc[4][4] = {};
    for (int k0 = 0; k0 < 2048; k0 += 32) {
#pragma unroll
        for (int j = 0; j < 4; ++j) gld16(gA[j] + k0, lwA[j]);
#pragma unroll
        for (int j = 0; j < 2; ++j) gld16(gB[j] + k0, lwB[j]);
        __syncthreads();
        f16x8 a[4], b[4];
#pragma unroll
        for (int mi = 0; mi < 4; ++mi) {
            f32x4 lo = *(const f32x4*)(lA + aoff[mi][0]);
            f32x4 hi = *(const f32x4*)(lA + aoff[mi][1]);
#pragma unroll
            for (int j = 0; j < 4; ++j) {
                a[mi][j] = (_Float16)lo[j];
                a[mi][4 + j] = (_Float16)hi[j];
            }
        }
#pragma unroll
        for (int ni = 0; ni < 4; ++ni) b[ni] = *(const f16x8*)(lB + boff[ni]);
        __syncthreads();   // frags in regs; next staging overlaps MFMAs below
#pragma unroll
        for (int mi = 0; mi < 4; ++mi)
#pragma unroll
            for (int ni = 0; ni < 4; ++ni)
                acc[mi][ni] = __builtin_amdgcn_mfma_f32_16x16x32_f16(
                    a[mi], b[ni], acc[mi][ni], 0, 0, 0);
    }
    float* dst = part + (size_t)blockIdx.z * TOK * HID;
    const int cn = lane & 15, rq = (lane >> 4) * 4;
#pragma unroll
    for (int mi = 0; mi < 4; ++mi)
#pragma unroll
        for (int r = 0; r < 4; ++r) {
            const int m = m0 + wM + mi * 16 + rq + r;
#pragma unroll
            for (int ni = 0; ni < 4; ++ni) {
                const int n = n0 + wN + ni * 16 + cn;
                dst[(size_t)m * HID + n] = acc[mi][ni][r];
            }
        }
}

// ---------------------------------------------------------------------------
// f16 NT GEMM, 64x128 tile, BK=32, 256 thr, waves 2x2 (wave 32x64, 2x4 MFMA).
// Both operands via gld16 + swizzle. Biases folded into K columns. Modes:
//  0 plain : f16 = v                       (P, WgT)
//  1 dual z: z0 down=relu(v) ; z1 g=v      (ldC=512)
//  2 addH  : f16 = v + addvH[idx]          (mixed)
//  3 addF  : f32 = v + addvF[idx]          (fuse)
// ---------------------------------------------------------------------------
template <int MODE>
__global__ __launch_bounds__(256) void gemmT(
    const _Float16* __restrict__ A, const _Float16* __restrict__ B,
    int K, int ldC,
    _Float16* __restrict__ outH, float* __restrict__ outF,
    const _Float16* __restrict__ addvH, const float* __restrict__ addvF,
    const _Float16* __restrict__ A2, const _Float16* __restrict__ B2,
    _Float16* __restrict__ outH2)
{
    __shared__ _Float16 lA[64 * 32];    // 4 KB
    __shared__ _Float16 lB[128 * 32];   // 8 KB
    const int tid = threadIdx.x, lane = tid & 63, wave = tid >> 6;
    int zz = 0;
    if constexpr (MODE == 1) {
        zz = blockIdx.z;
        if (zz) { A = A2; B = B2; outH = outH2; }
    }
    const int m0 = blockIdx.x * 64;
    const int n0 = blockIdx.y * 128;
    const int wM = (wave & 1) * 32;
    const int wN = (wave >> 1) * 64;

    // A: 256 chunks (64 rows x 4 slots) -> 1 per thread
    const int qa = tid, rowa = qa >> 2;
    const int kca = ((qa & 3) - (rowa >> 1)) & 3;
    const _Float16* gA = A + (size_t)(m0 + rowa) * K + kca * 8;
    _Float16* lwA = lA + qa * 8;
    // B: 512 chunks -> 2 per thread
    const _Float16* gB[2]; _Float16* lwB[2];
#pragma unroll
    for (int j = 0; j < 2; ++j) {
        const int q = j * 256 + tid;
        const int row = q >> 2;
        const int kc = ((q & 3) - (row >> 1)) & 3;
        gB[j] = B + (size_t)(n0 + row) * K + kc * 8;
        lwB[j] = lB + q * 8;
    }
    const int fr = lane & 15, kcq = lane >> 4;
    int aoff[2], boff[4];
#pragma unroll
    for (int mi = 0; mi < 2; ++mi) {
        const int r = wM + mi * 16 + fr;
        aoff[mi] = r * 32 + ((kcq + (fr >> 1)) & 3) * 8;
    }
#pragma unroll
    for (int ni = 0; ni < 4; ++ni) {
        const int r = wN + ni * 16 + fr;
        boff[ni] = r * 32 + ((kcq + (fr >> 1)) & 3) * 8;
    }

    f32x4 acc[2][4] = {};
    for (int k0 = 0; k0 < K; k0 += 32) {
        gld16(gA + k0, lwA);
        gld16(gB[0] + k0, lwB[0]);
        gld16(gB[1] + k0, lwB[1]);
        __syncthreads();
        f16x8 a[2], b[4];
#pragma unroll
        for (int mi = 0; mi < 2; ++mi) a[mi] = *(const f16x8*)(lA + aoff[mi]);
#pragma unroll
        for (int ni = 0; ni < 4; ++ni) b[ni] = *(const f16x8*)(lB + boff[ni]);
        __syncthreads();
#pragma unroll
        for (int mi = 0; mi < 2; ++mi)
#pragma unroll
            for (int ni = 0; ni < 4; ++ni)
                acc[mi][ni] = __builtin_amdgcn_mfma_f32_16x16x32_f16(
                    a[mi], b[ni], acc[mi][ni], 0, 0, 0);
    }
    const int cn = lane & 15, rq = (lane >> 4) * 4;
#pragma unroll
    for (int mi = 0; mi < 2; ++mi)
#pragma unroll
        for (int r = 0; r < 4; ++r) {
            const int m = m0 + wM + mi * 16 + rq + r;
#pragma unroll
            for (int ni = 0; ni < 4; ++ni) {
                const int n = n0 + wN + ni * 16 + cn;
                const size_t idx = (size_t)m * ldC + n;
                const float v = acc[mi][ni][r];
                if constexpr (MODE == 0) {
                    outH[idx] = (_Float16)v;
                } else if constexpr (MODE == 1) {
                    outH[idx] = (_Float16)(zz ? v : (v > 0.f ? v : 0.f));
                } else if constexpr (MODE == 2) {
                    outH[idx] = (_Float16)(v + (float)addvH[idx]);
                } else {
                    outF[idx] = v + addvF[idx];
                }
            }
        }
}

// ---------------------------------------------------------------------------
// split-K reduce + bias + LN. h=p0+p1+dense_b; pn=h+it; ai=LN(pn).
// ai/pn stride PSTR with col1024=1, cols 1025..1055=0 (bias folding).
// ---------------------------------------------------------------------------
__global__ __launch_bounds__(256) void ln_fused(
    const float* __restrict__ part, const float* __restrict__ dbias,
    const float* __restrict__ it, const float* __restrict__ gam,
    const float* __restrict__ bet, _Float16* __restrict__ h16,
    _Float16* __restrict__ ai, _Float16* __restrict__ pn)
{
    const int n = blockIdx.x, tid = threadIdx.x;
    const int lane = tid & 63, wave = tid >> 6;
    const size_t base = (size_t)n * 1024 + tid * 4;
    f32x4 h = *(const f32x4*)(dbias + tid * 4);
    h += *(const f32x4*)(part + base);
    h += *(const f32x4*)(part + (size_t)TOK * HID + base);
    f16x4 hv;
#pragma unroll
    for (int j = 0; j < 4; ++j) hv[j] = (_Float16)h[j];
    *(f16x4*)(h16 + base) = hv;
    f32x4 x = h + *(const f32x4*)(it + base);
    float s = x[0] + x[1] + x[2] + x[3];
    float q = x[0] * x[0] + x[1] * x[1] + x[2] * x[2] + x[3] * x[3];
#pragma unroll
    for (int off = 1; off < 64; off <<= 1) {
        s += __shfl_xor(s, off);
        q += __shfl_xor(q, off);
    }
    __shared__ float rs[4], rq[4];
    if (lane == 0) { rs[wave] = s; rq[wave] = q; }
    __syncthreads();
    s = rs[0] + rs[1] + rs[2] + rs[3];
    q = rq[0] + rq[1] + rq[2] + rq[3];
    const float mu = s * (1.f / 1024.f);
    const float var = q * (1.f / 1024.f) - mu * mu;
    const float rstd = rsqrtf(var + 1e-12f);
    f32x4 gv = *(const f32x4*)(gam + tid * 4);
    f32x4 bv = *(const f32x4*)(bet + tid * 4);
    f16x4 av, pv;
#pragma unroll
    for (int j = 0; j < 4; ++j) {
        const float y = (x[j] - mu) * rstd * gv[j] + bv[j];
        av[j] = (_Float16)y;
        pv[j] = (_Float16)x[j];
    }
    const size_t pb = (size_t)n * PSTR + tid * 4;
    *(f16x4*)(ai + pb) = av;
    *(f16x4*)(pn + pb) = pv;
    if (tid < 8) {
        f16x4 z;
#pragma unroll
        for (int j = 0; j < 4; ++j) z[j] = (_Float16)0.f;
        if (tid == 0) z[0] = (_Float16)1.f;
        const size_t qb = (size_t)n * PSTR + 1024 + tid * 4;
        *(f16x4*)(ai + qb) = z;
        *(f16x4*)(pn + qb) = z;
    }
}

__global__ __launch_bounds__(256) void ln_out(
    const float* __restrict__ fuse, const float* __restrict__ gam,
    const float* __restrict__ bet, float* __restrict__ outp)
{
    const int n = blockIdx.x, tid = threadIdx.x;
    const int lane = tid & 63, wave = tid >> 6;
    const size_t base = (size_t)n * 1024 + tid * 4;
    f32x4 x = *(const f32x4*)(fuse + base);
    float s = x[0] + x[1] + x[2] + x[3];
    float q = x[0] * x[0] + x[1] * x[1] + x[2] * x[2] + x[3] * x[3];
#pragma unroll
    for (int off = 1; off < 64; off <<= 1) {
        s += __shfl_xor(s, off);
        q += __shfl_xor(q, off);
    }
    __shared__ float rs[4], rq[4];
    if (lane == 0) { rs[wave] = s; rq[wave] = q; }
    __syncthreads();
    s = rs[0] + rs[1] + rs[2] + rs[3];
    q = rq[0] + rq[1] + rq[2] + rq[3];
    const float mu = s * (1.f / 1024.f);
    const float var = q * (1.f / 1024.f) - mu * mu;
    const float rstd = rsqrtf(var + 1e-12f);
    f32x4 gv = *(const f32x4*)(gam + tid * 4);
    f32x4 bv = *(const f32x4*)(bet + tid * 4);
    f32x4 y;
#pragma unroll
    for (int j = 0; j < 4; ++j) y[j] = (x[j] - mu) * rstd * gv[j] + bv[j];
    *(f32x4*)(outp + base) = y;
}

// ---------------------------------------------------------------------------
// scores + softmax over T; wdownP = [probs*down | probs_f16 | zeros] (MSTR).
// ---------------------------------------------------------------------------
__global__ __launch_bounds__(256) void scores2(
    const _Float16* __restrict__ pn, const float* __restrict__ U9,
    const float* __restrict__ cts,
    const _Float16* __restrict__ down, const _Float16* __restrict__ g,
    _Float16* __restrict__ wdownP)
{
    const int n = blockIdx.x, tid = threadIdx.x;
    const int lane = tid & 63, wave = tid >> 6;
    const _Float16* prow = pn + (size_t)n * PSTR;
    float a9[9] = {};
#pragma unroll
    for (int j = 0; j < 4; ++j) {
        const int h = tid + j * 256;
        const float ph = (float)prow[h];
        const float* u = U9 + h * 12;
        f32x4 u0 = *(const f32x4*)u;
        f32x4 u1 = *(const f32x4*)(u + 4);
#pragma unroll
        for (int k = 0; k < 4; ++k) { a9[k] += ph * u0[k]; a9[4 + k] += ph * u1[k]; }
        a9[8] += ph * u[8];
    }
#pragma unroll
    for (int off = 1; off < 64; off <<= 1)
#pragma unroll
        for (int k = 0; k < 9; ++k) a9[k] += __shfl_xor(a9[k], off);
    __shared__ float red[4][9];
    __shared__ float sd[8];
    __shared__ float pl[8];
    if (lane == 0)
#pragma unroll
        for (int k = 0; k < 9; ++k) red[wave][k] = a9[k];
    const int c0i = tid * 2;
    const size_t dbase = (size_t)n * 512;
    const float d0 = (float)down[dbase + c0i];
    const float d1 = (float)down[dbase + c0i + 1];
    float pz = d0 * (float)g[dbase + c0i] + d1 * (float)g[dbase + c0i + 1];
#pragma unroll
    for (int off = 1; off < 32; off <<= 1) pz += __shfl_xor(pz, off);
    if ((lane & 31) == 0) sd[wave * 2 + (lane >> 5)] = pz;
    __syncthreads();
    if (tid == 0) {
        float qb = cts[8];
#pragma unroll
        for (int w = 0; w < 4; ++w) qb += red[w][8];
        float sc[8];
        float mx = -1e30f;
#pragma unroll
        for (int t = 0; t < 8; ++t) {
            float v = sd[t] + cts[t] + qb;
#pragma unroll
            for (int w = 0; w < 4; ++w) v += red[w][t];
            sc[t] = v;
            mx = fmaxf(mx, v);
        }
        float sum = 0.f;
#pragma unroll
        for (int t = 0; t < 8; ++t) { sc[t] = expf(sc[t] - mx); sum += sc[t]; }
        const float inv = 1.f / sum;
#pragma unroll
        for (int t = 0; t < 8; ++t) pl[t] = sc[t] * inv;
    }
    __syncthreads();
    _Float16* wd = wdownP + (size_t)n * MSTR;
    const float pr = pl[c0i >> 6];
    wd[c0i]     = (_Float16)(pr * d0);
    wd[c0i + 1] = (_Float16)(pr * d1);
    if (tid < 64)
        wd[512 + tid] = (tid < 8) ? (_Float16)pl[tid] : (_Float16)0.f;
}

// ---------------------------------------------------------------------------
// prep: all weight conversions, reshapes, bias-column folding
// ---------------------------------------------------------------------------
__device__ inline void cvt_seg(const float* __restrict__ s, _Float16* __restrict__ d,
                               int n4, int gid, int gsz)
{
    for (int i = gid; i < n4; i += gsz) {
        f32x4 v = ((const f32x4*)s)[i];
        f16x4 o;
        o[0] = (_Float16)v[0]; o[1] = (_Float16)v[1];
        o[2] = (_Float16)v[2]; o[3] = (_Float16)v[3];
        ((f16x4*)d)[i] = o;
    }
}

__global__ __launch_bounds__(256) void prep_all(
    const float* dw, _Float16* o_dw,
    const float* vw, _Float16* o_vw,
    const float* kw, _Float16* o_kw,
    const float* upw, const float* upb, _Float16* o_upg, _Float16* o_upmix,
    const float* dnw, const float* dnb, _Float16* o_dn)
{
    const int gid = blockIdx.x * 256 + threadIdx.x;
    const int gsz = gridDim.x * 256;
    cvt_seg(dw, o_dw, HID * IDIM / 4, gid, gsz);
    cvt_seg(vw, o_vw, HID * HID / 4, gid, gsz);
    cvt_seg(kw, o_kw, HID * HID / 4, gid, gsz);
    for (int i = gid; i < 8 * HID * 64; i += gsz) {
        const int d = i & 63;
        const int h = (i >> 6) & 1023;
        const int t = i >> 16;
        const _Float16 v = (_Float16)upw[i];
        o_upg[(size_t)(t * 64 + d) * 1024 + h] = v;
        o_upmix[(size_t)h * MSTR + t * 64 + d] = v;
    }
    for (int j = gid; j < 1024 * 64; j += gsz) {
        const int h = j >> 6, c = j & 63;
        o_upmix[(size_t)h * MSTR + 512 + c] =
            (c < 8) ? (_Float16)upb[c * 1024 + h] : (_Float16)0.f;
    }
    for (int i = gid; i < 512 * 1024; i += gsz) {
        const int td = i >> 10, h = i & 1023;
        o_dn[(size_t)td * PSTR + h] = (_Float16)dnw[i];
    }
    for (int j = gid; j < 512 * 32; j += gsz) {
        const int td = j >> 5, c = j & 31;
        o_dn[(size_t)td * PSTR + 1024 + c] =
            (c == 0) ? (_Float16)dnb[td] : (_Float16)0.f;
    }
}

__global__ __launch_bounds__(256) void transpose_q(
    const float* __restrict__ in, _Float16* __restrict__ outp)
{
    __shared__ float t[32][33];
    const int bx = blockIdx.x * 32;
    const int by = blockIdx.y * 32;
    const int tx = threadIdx.x & 31, ty = threadIdx.x >> 5;
#pragma unroll
    for (int j = 0; j < 32; j += 8)
        t[ty + j][tx] = in[(size_t)(by + ty + j) * 1024 + bx + tx];
    __syncthreads();
#pragma unroll
    for (int j = 0; j < 32; j += 8)
        outp[(size_t)(bx + ty + j) * 1024 + by + tx] = (_Float16)t[tx][ty + j];
}

// sv1: V[q,t] = key_w[q,:]·up_b[t,:] ; cts[8] = query_b·key_b
__global__ __launch_bounds__(256) void sv1(
    const float* __restrict__ key_w, const float* __restrict__ up_b,
    const float* __restrict__ query_b, const float* __restrict__ key_b,
    float* __restrict__ V, float* __restrict__ cts)
{
    const int b = blockIdx.x, tid = threadIdx.x;
    if (b < 32) {
        const int q = b * 32 + (tid >> 3);
        const int t = tid & 7;
        const f32x4* kr = (const f32x4*)(key_w + (size_t)q * 1024);
        const f32x4* ur = (const f32x4*)(up_b + (size_t)t * 1024);
        float acc = 0.f;
        for (int i = 0; i < 256; ++i) {
            f32x4 a = kr[i], u = ur[i];
            acc += a[0] * u[0] + a[1] * u[1] + a[2] * u[2] + a[3] * u[3];
        }
        V[q * 8 + t] = acc;
    } else {
        float acc = 0.f;
        for (int q = tid; q < 1024; q += 256) acc += query_b[q] * key_b[q];
#pragma unroll
        for (int off = 1; off < 64; off <<= 1) acc += __shfl_xor(acc, off);
        __shared__ float r[4];
        if ((tid & 63) == 0) r[tid >> 6] = acc;
        __syncthreads();
        if (tid == 0) cts[8] = r[0] + r[1] + r[2] + r[3];
    }
}

// sv2: U9 cols 0-7 (w_qT·V) + col 8 (key_b@query_w via w_qT);
//      WgTB bias col (P·query_b) + zero pads; cts 0-7 (query_b·V)
__global__ __launch_bounds__(256) void sv2(
    const _Float16* __restrict__ w_qT, const _Float16* __restrict__ P,
    const float* __restrict__ V, const float* __restrict__ query_b,
    const float* __restrict__ key_b,
    float* __restrict__ U9, _Float16* __restrict__ WgTB, float* __restrict__ cts)
{
    const int b = blockIdx.x, tid = threadIdx.x;
    if (b < 32) {
        const int h = b * 32 + (tid >> 3);
        const int t = tid & 7;
        const _Float16* wr = w_qT + (size_t)h * 1024;
        float acc = 0.f;
        for (int q0 = 0; q0 < 1024; q0 += 4) {
            f16x4 w = *(const f16x4*)(wr + q0);
            acc += (float)w[0] * V[q0 * 8 + t] + (float)w[1] * V[(q0 + 1) * 8 + t]
                 + (float)w[2] * V[(q0 + 2) * 8 + t] + (float)w[3] * V[(q0 + 3) * 8 + t];
        }
        U9[h * 12 + t] = acc;
    } else if (b < 36) {
        const int h1 = (b - 32) * 256 + tid;
        const _Float16* wr = w_qT + (size_t)h1 * 1024;
        float acc = 0.f;
        for (int q0 = 0; q0 < 1024; q0 += 8) {
            f16x8 w = *(const f16x8*)(wr + q0);
            f32x4 k0 = *(const f32x4*)(key_b + q0);
            f32x4 k1 = *(const f32x4*)(key_b + q0 + 4);
#pragma unroll
            for (int j = 0; j < 4; ++j)
                acc += (float)w[j] * k0[j] + (float)w[4 + j] * k1[j];
        }
        U9[h1 * 12 + 8] = acc;
    } else if (b < 38) {
        const int td = (b - 36) * 256 + tid;
        const _Float16* pr = P + (size_t)td * 1024;
        float acc = 0.f;
        for (int q0 = 0; q0 < 1024; q0 += 8) {
            f16x8 w = *(const f16x8*)(pr + q0);
            f32x4 k0 = *(const f32x4*)(query_b + q0);
            f32x4 k1 = *(const f32x4*)(query_b + q0 + 4);
#pragma unroll
            for (int j = 0; j < 4; ++j)
                acc += (float)w[j] * k0[j] + (float)w[4 + j] * k1[j];
        }
        WgTB[(size_t)td * PSTR + 1024] = (_Float16)acc;
        for (int c = 1; c < 32; ++c)
            WgTB[(size_t)td * PSTR + 1024 + c] = (_Float16)0.f;
    } else {
        const int t = tid >> 5;
        float acc = 0.f;
        for (int q = tid & 31; q < 1024; q += 32) acc += V[q * 8 + t] * query_b[q];
#pragma unroll
        for (int off = 1; off < 32; off <<= 1) acc += __shfl_xor(acc, off);
        if ((tid & 31) == 0) cts[t] = acc;
    }
}

// ---------------------------------------------------------------------------
extern "C" void kernel_launch(void* const* d_in, const int* in_sizes, int n_in,
                              void* d_out, int out_size, void* d_ws, size_t ws_size,
                              hipStream_t stream)
{
    const float* hs      = (const float*)d_in[0];
    const float* it      = (const float*)d_in[1];
    const float* dense_w = (const float*)d_in[2];
    const float* dense_b = (const float*)d_in[3];
    const float* ln_g    = (const float*)d_in[4];
    const float* ln_b    = (const float*)d_in[5];
    const float* down_w  = (const float*)d_in[6];
    const float* down_b  = (const float*)d_in[7];
    const float* up_w    = (const float*)d_in[8];
    const float* up_b    = (const float*)d_in[9];
    const float* key_w   = (const float*)d_in[10];
    const float* key_b   = (const float*)d_in[11];
    const float* query_w = (const float*)d_in[12];
    const float* query_b = (const float*)d_in[13];
    const float* value_w = (const float*)d_in[14];
    float* outp = (float*)d_out;
    (void)in_sizes; (void)n_in; (void)out_size; (void)ws_size;

    const size_t MiB = 1048576ull;
    char* base = (char*)d_ws;
    _Float16* w_dense = (_Float16*)(base);                    // 8 MiB
    _Float16* w_value = (_Float16*)(base + 8 * MiB);          // 2
    _Float16* w_key16 = (_Float16*)(base + 10 * MiB);         // 2
    _Float16* w_qT    = (_Float16*)(base + 12 * MiB);         // 2
    _Float16* w_upg   = (_Float16*)(base + 14 * MiB);         // 1
    _Float16* upmixP  = (_Float16*)(base + 15 * MiB);         // 1.125 [1024xMSTR]
    _Float16* w_downB = (_Float16*)(base + 16 * MiB + 262144);// 1.03  [512xPSTR]
    _Float16* WgTB    = (_Float16*)(base + 17 * MiB + 524288);// 1.03  [512xPSTR]
    _Float16* P       = (_Float16*)(base + 18 * MiB + 786432);// 1     [512x1024]
    float*    U9      = (float*)(base + 19 * MiB + 786432);   // 48 KiB [1024][12]
    float*    V       = (float*)(base + 19 * MiB + 835584);   // 32 KiB
    float*    cts     = (float*)(base + 19 * MiB + 868352);   // 64 B
    _Float16* h16     = (_Float16*)(base + 20 * MiB);         // 8 MiB
    _Float16* ai      = (_Float16*)(base + 28 * MiB);         // 8.25 [4096xPSTR]
    _Float16* pn      = (_Float16*)(base + 36 * MiB + 262144);// 8.25
    char* X = base + 45 * MiB;                                // 32 MiB region
    float*    part   = (float*)X;                             // 2x16 MiB (dense)
    _Float16* down   = (_Float16*)X;                          // 4 MiB (post-LN)
    _Float16* g      = (_Float16*)(X + 4 * MiB);              // 4 MiB
    _Float16* wdownP = (_Float16*)(X + 8 * MiB);              // 4.5 [4096xMSTR]
    float*    fuse   = (float*)(X + 13 * MiB);                // 16 MiB
    _Float16* mixed  = ai;                                    // reuse (dead)

    // 1. weight prep (cvt + reshapes + bias-column folding)
    prep_all<<<1024, 256, 0, stream>>>(dense_w, w_dense, value_w, w_value,
                                       key_w, w_key16, up_w, up_b, w_upg, upmixP,
                                       down_w, down_b, w_downB);
    // 2. w_qT = query_w^T (f16)
    transpose_q<<<dim3(32, 32), 256, 0, stream>>>(query_w, w_qT);
    // 3. V[q,t], cts[8]
    sv1<<<33, 256, 0, stream>>>(key_w, up_b, query_b, key_b, V, cts);
    // 4. dense partials (sk=2), both operands via global_load_lds
    gemm_dense<<<dim3(32, 8, 2), 256, 0, stream>>>(hs, w_dense, part);
    // 5. reduce + LN -> h16, ai, pn (padded)
    ln_fused<<<TOK, 256, 0, stream>>>(part, dense_b, it, ln_g, ln_b, h16, ai, pn);
    // 6. P = w_upg @ w_key16^T   [512x1024]
    gemmT<0><<<dim3(8, 8), 256, 0, stream>>>(
        w_upg, w_key16, HID, HID, P, nullptr, nullptr, nullptr,
        nullptr, nullptr, nullptr);
    // 7. WgTB(cols 0..1023) = P @ w_qT^T   [512x1024], ldC=PSTR
    gemmT<0><<<dim3(8, 8), 256, 0, stream>>>(
        P, w_qT, HID, PSTR, WgTB, nullptr, nullptr, nullptr,
        nullptr, nullptr, nullptr);
    // 8. U9, WgTB bias col, cts 0-7
    sv2<<<39, 256, 0, stream>>>(w_qT, P, V, query_b, key_b, U9, WgTB, cts);
    // 9. dual: down = relu(ai @ w_downB^T); g = pn @ WgTB^T   (K=PSTR)
    gemmT<1><<<dim3(64, 4, 2), 256, 0, stream>>>(
        ai, w_downB, PSTR, 512, down, nullptr, nullptr, nullptr,
        pn, WgTB, g);
    // 10. scores -> softmax -> wdownP (incl probs cols + zero pad)
    scores2<<<TOK, 256, 0, stream>>>(pn, U9, cts, down, g, wdownP);
    // 11. mixed = wdownP @ upmixP^T + h16   (K=MSTR covers probs@up_b)
    gemmT<2><<<dim3(64, 8), 256, 0, stream>>>(
        wdownP, upmixP, MSTR, HID, mixed, nullptr, h16, nullptr,
        nullptr, nullptr, nullptr);
    // 12. fuse = mixed @ w_value^T + it (f32)
    gemmT<3><<<dim3(64, 8), 256, 0, stream>>>(
        mixed, w_value, HID, HID, nullptr, fuse, nullptr, it,
        nullptr, nullptr, nullptr);
    // 13. out = LN(fuse)
    ln_out<<<TOK, 256, 0, stream>>>(fuse, ln_g, ln_b, outp);
}